// Round 1
// baseline (567.683 us; speedup 1.0000x reference)
//
#include <hip/hip_runtime.h>
#include <hip/hip_bf16.h>

#define B_ 2048
#define C_ 50000
#define D_ 128
#define NT_ (C_ / 16)      // 3125 column tiles of 16
#define S_ 20.0f
#define MARGIN_ 0.1f
#define EPSC_ 1e-07f
#define C1N_ 2.0f          // fixed softmax offset, unscaled path (wf <= 1.06)
#define C2N_ 22.0f         // fixed softmax offset, scaled path (20*wf <= 21.2)

typedef __bf16 bf16x8 __attribute__((ext_vector_type(8)));
typedef float  f32x4  __attribute__((ext_vector_type(4)));

static __device__ __forceinline__ unsigned short f2bf(float f) {
  unsigned u = __float_as_uint(f);
  u += 0x7FFFu + ((u >> 16) & 1u);     // round-to-nearest-even
  return (unsigned short)(u >> 16);
}
static __device__ __forceinline__ float bf2f(unsigned short h) {
  return __uint_as_float(((unsigned)h) << 16);
}

// K1: row-normalize x (2048 rows) and W (50000 rows) -> bf16. One wave per row.
__global__ __launch_bounds__(256) void k_norm(const float* __restrict__ x,
                                              const float* __restrict__ W,
                                              unsigned short* __restrict__ e_bf,
                                              unsigned short* __restrict__ wn_bf) {
  int r = blockIdx.x * 4 + (threadIdx.x >> 6);
  int lane = threadIdx.x & 63;
  if (r >= B_ + C_) return;
  const float* src = (r < B_) ? (x + (size_t)r * D_) : (W + (size_t)(r - B_) * D_);
  float2 v = ((const float2*)src)[lane];
  float ss = v.x * v.x + v.y * v.y;
#pragma unroll
  for (int m = 1; m < 64; m <<= 1) ss += __shfl_xor(ss, m, 64);
  float sc = 1.0f / fmaxf(sqrtf(ss), 1e-12f);
  unsigned short* dst = (r < B_) ? (e_bf + (size_t)r * D_) : (wn_bf + (size_t)(r - B_) * D_);
  ((ushort2*)dst)[lane] = make_ushort2(f2bf(v.x * sc), f2bf(v.y * sc));
}

// K2: bf16 MFMA GEMM (no wf materialization) + fused fixed-offset exp sums.
// Each wave: 64 rows (4 M-tiles of 16) x grid-stride over 16-col tiles.
__global__ __launch_bounds__(256) void k_stats(const unsigned short* __restrict__ e_bf,
                                               const unsigned short* __restrict__ wn_bf,
                                               const float* __restrict__ bias,
                                               float* __restrict__ sum1,
                                               float* __restrict__ sum2) {
  const int wave = threadIdx.x >> 6;
  const int lane = threadIdx.x & 63;
  const int quad = lane >> 4;
  const int l16  = lane & 15;
  const int rowbase = blockIdx.y * 64;

  bf16x8 afrag[4][4];                      // [mtile][kstep]
#pragma unroll
  for (int t = 0; t < 4; ++t) {
    const unsigned short* ap = e_bf + (size_t)(rowbase + t * 16 + l16) * D_ + quad * 8;
#pragma unroll
    for (int k = 0; k < 4; ++k) afrag[t][k] = *(const bf16x8*)(ap + k * 32);
  }

  float s1a[4][4] = {};                    // [mtile][reg] lane-local partial sums
  float s2a[4][4] = {};

  for (int ct = blockIdx.x * 4 + wave; ct < NT_; ct += 256) {
    const int n0 = ct * 16;
    const unsigned short* bp = wn_bf + (size_t)(n0 + l16) * D_ + quad * 8;
    bf16x8 bfrag[4];
#pragma unroll
    for (int k = 0; k < 4; ++k) bfrag[k] = *(const bf16x8*)(bp + k * 32);
    float bb = bias[n0 + l16];

    f32x4 acc[4] = {};
#pragma unroll
    for (int k = 0; k < 4; ++k)
#pragma unroll
      for (int t = 0; t < 4; ++t)
        acc[t] = __builtin_amdgcn_mfma_f32_16x16x32_bf16(afrag[t][k], bfrag[k], acc[t], 0, 0, 0);

#pragma unroll
    for (int t = 0; t < 4; ++t)
#pragma unroll
      for (int r = 0; r < 4; ++r) {
        float wf = acc[t][r] + bb;
        s1a[t][r] += __expf(wf - C1N_);
        s2a[t][r] += __expf(fmaf(wf, S_, -C2N_));
      }
  }

  // reduce across the 16 cols (lanes sharing a quad), then cross-wave via LDS
  __shared__ float sb1[4][64];
  __shared__ float sb2[4][64];
#pragma unroll
  for (int t = 0; t < 4; ++t)
#pragma unroll
    for (int r = 0; r < 4; ++r) {
      float a = s1a[t][r], c = s2a[t][r];
#pragma unroll
      for (int m = 1; m < 16; m <<= 1) {
        a += __shfl_xor(a, m, 64);
        c += __shfl_xor(c, m, 64);
      }
      if (l16 == 0) {
        sb1[wave][t * 16 + quad * 4 + r] = a;
        sb2[wave][t * 16 + quad * 4 + r] = c;
      }
    }
  __syncthreads();
  int tid = threadIdx.x;
  if (tid < 64) {
    float v1 = sb1[0][tid] + sb1[1][tid] + sb1[2][tid] + sb1[3][tid];
    float v2 = sb2[0][tid] + sb2[1][tid] + sb2[2][tid] + sb2[3][tid];
    atomicAdd(&sum1[rowbase + tid], v1);
    atomicAdd(&sum2[rowbase + tid], v2);
  }
}

// K3: recompute GEMM, write prediction = exp(wf - C1)/sum1.
__global__ __launch_bounds__(256) void k_pred(const unsigned short* __restrict__ e_bf,
                                              const unsigned short* __restrict__ wn_bf,
                                              const float* __restrict__ bias,
                                              const float* __restrict__ sum1,
                                              float* __restrict__ out) {
  const int wave = threadIdx.x >> 6;
  const int lane = threadIdx.x & 63;
  const int quad = lane >> 4;
  const int l16  = lane & 15;
  const int rowbase = blockIdx.y * 64;

  bf16x8 afrag[4][4];
#pragma unroll
  for (int t = 0; t < 4; ++t) {
    const unsigned short* ap = e_bf + (size_t)(rowbase + t * 16 + l16) * D_ + quad * 8;
#pragma unroll
    for (int k = 0; k < 4; ++k) afrag[t][k] = *(const bf16x8*)(ap + k * 32);
  }

  float inv[4][4];
  float* op[4][4];
#pragma unroll
  for (int t = 0; t < 4; ++t)
#pragma unroll
    for (int r = 0; r < 4; ++r) {
      int row = rowbase + t * 16 + quad * 4 + r;
      inv[t][r] = 1.0f / sum1[row];
      op[t][r] = out + (size_t)row * C_;
    }

  for (int ct = blockIdx.x * 4 + wave; ct < NT_; ct += 256) {
    const int n0 = ct * 16;
    const unsigned short* bp = wn_bf + (size_t)(n0 + l16) * D_ + quad * 8;
    bf16x8 bfrag[4];
#pragma unroll
    for (int k = 0; k < 4; ++k) bfrag[k] = *(const bf16x8*)(bp + k * 32);
    float bb = bias[n0 + l16];

    f32x4 acc[4] = {};
#pragma unroll
    for (int k = 0; k < 4; ++k)
#pragma unroll
      for (int t = 0; t < 4; ++t)
        acc[t] = __builtin_amdgcn_mfma_f32_16x16x32_bf16(afrag[t][k], bfrag[k], acc[t], 0, 0, 0);

#pragma unroll
    for (int t = 0; t < 4; ++t)
#pragma unroll
      for (int r = 0; r < 4; ++r) {
        float wf = acc[t][r] + bb;
        op[t][r][n0 + l16] = __expf(wf - C1N_) * inv[t][r];
      }
  }
}

// K4: loss. One thread per row: label dot, margin, fixed-offset logsumexp.
__global__ __launch_bounds__(64) void k_loss(const unsigned short* __restrict__ e_bf,
                                             const unsigned short* __restrict__ wn_bf,
                                             const float* __restrict__ bias,
                                             const int* __restrict__ labels,
                                             const float* __restrict__ sum2,
                                             float* __restrict__ loss_out) {
  int row = blockIdx.x * 64 + threadIdx.x;
  int lab = labels[row];
  const unsigned short* ep = e_bf + (size_t)row * D_;
  const unsigned short* wp = wn_bf + (size_t)lab * D_;
  float dot = 0.f;
#pragma unroll 8
  for (int k = 0; k < D_; ++k) dot += bf2f(ep[k]) * bf2f(wp[k]);
  float wf = dot + bias[lab];
  float wc = fminf(fmaxf(wf, -1.0f + EPSC_), 1.0f - EPSC_);
  float target = cosf(acosf(wc) + MARGIN_);
  float s2 = sum2[row];
  s2 = s2 - __expf(fmaf(wf, S_, -C2N_)) + __expf(fmaf(target, S_, -C2N_));
  float lossr = (C2N_ + logf(s2)) - S_ * target;   // -log p[label]
#pragma unroll
  for (int m = 1; m < 64; m <<= 1) lossr += __shfl_xor(lossr, m, 64);
  if (threadIdx.x == 0) atomicAdd(loss_out, lossr * (1.0f / (float)B_));
}

extern "C" void kernel_launch(void* const* d_in, const int* in_sizes, int n_in,
                              void* d_out, int out_size, void* d_ws, size_t ws_size,
                              hipStream_t stream) {
  const float* x = (const float*)d_in[0];
  const float* W = (const float*)d_in[1];
  const float* b = (const float*)d_in[2];
  const int* labels = (const int*)d_in[3];
  float* out = (float*)d_out;

  char* ws = (char*)d_ws;
  unsigned short* wn_bf = (unsigned short*)ws;                         // 12,800,000 B
  unsigned short* e_bf  = (unsigned short*)(ws + 12800000);            //    524,288 B
  float* sum1 = (float*)(ws + 12800000 + 524288);                      //      8,192 B
  float* sum2 = sum1 + B_;                                             //      8,192 B

  hipMemsetAsync(sum1, 0, 2 * B_ * sizeof(float), stream);
  float* loss_out = out + (size_t)B_ * C_;
  hipMemsetAsync(loss_out, 0, sizeof(float), stream);

  k_norm<<<dim3((B_ + C_ + 3) / 4), dim3(256), 0, stream>>>(x, W, e_bf, wn_bf);
  k_stats<<<dim3(64, 32), dim3(256), 0, stream>>>(e_bf, wn_bf, b, sum1, sum2);
  k_pred<<<dim3(64, 32), dim3(256), 0, stream>>>(e_bf, wn_bf, b, sum1, out);
  k_loss<<<dim3(B_ / 64), dim3(64), 0, stream>>>(e_bf, wn_bf, b, labels, sum2, loss_out);
}